// Round 4
// baseline (5962.788 us; speedup 1.0000x reference)
//
#include <hip/hip_runtime.h>
#include <math.h>

#define B_ 8
#define C_ 512
#define W_ 64
#define H_ 32
#define HID_ 256
#define G_ 1280
#define WH_ (W_*H_)           // 2048
#define CELL_STRIDE (B_*HID_) // 2048 floats per (w,h) cell in hbuf/cbuf

__device__ __forceinline__ float sigmoidf_(float x) {
    return 1.0f / (1.0f + __expf(-x));
}

__device__ __forceinline__ float tanhf_(float x) {
    float ax = fabsf(x);
    float e = __expf(-2.0f * ax);
    float t = (1.0f - e) / (1.0f + e);
    return copysignf(t, x);
}

// ---------------------------------------------------------------------------
// A0: transpose x (B,C,W,H) = [bc][wh] row-major  ->  xT [wh][bc]
// ---------------------------------------------------------------------------
__global__ __launch_bounds__(256) void k_transpose_x(const float* __restrict__ x,
                                                     float* __restrict__ xT) {
    __shared__ float tile[64][65];
    int bc0 = blockIdx.x * 64;
    int wh0 = blockIdx.y * 64;
    int xcol = threadIdx.x & 63;
    int yrow = threadIdx.x >> 6;
    for (int yy = yrow; yy < 64; yy += 4)
        tile[yy][xcol] = x[(size_t)(bc0 + yy) * WH_ + wh0 + xcol];
    __syncthreads();
    for (int yy = yrow; yy < 64; yy += 4)
        xT[(size_t)(wh0 + yy) * (B_*C_) + bc0 + xcol] = tile[xcol][yy];
}

// ---------------------------------------------------------------------------
// A: GEMM  xp[m][g] = sum_c A[m][c]*Wx[c][g] + bias[g],  m = wh*8+b (16384)
// BM=64, BN=128, BK=32; 256 threads; micro-tile 8m x 4n (row-contiguous stores)
// ---------------------------------------------------------------------------
#define BM 64
#define BN 128
#define BK 32
#define AS_STRIDE 68    // [k][m] padded
#define BS_STRIDE 132   // [k][n] padded

__global__ __launch_bounds__(256) void k_xproj(const float* __restrict__ xT,
                                               const float* __restrict__ Wx,
                                               const float* __restrict__ bias,
                                               float* __restrict__ xp) {
    __shared__ float As[BK * AS_STRIDE];
    __shared__ float Bs[BK * BS_STRIDE];

    int bid = blockIdx.x;
    int xcd = bid & 7;
    int slot = bid >> 3;             // 0..319
    int mt = xcd * 32 + slot / 10;   // 0..255
    int nt = slot % 10;              // 0..9
    int m0 = mt * BM, n0 = nt * BN;
    int tid = threadIdx.x;

    int tm  = (tid >> 5) * 8;        // 0..56 (8 rows per thread)
    int tn4 = (tid & 31) * 4;        // 0..124 (4 contiguous n per thread)

    float4 acc[8];
#pragma unroll
    for (int i = 0; i < 8; ++i) { acc[i].x = acc[i].y = acc[i].z = acc[i].w = 0.f; }

    int ar = tid >> 2, aq = tid & 3;   // A staging: row 0..63, float4 idx
    int br = tid >> 3, bq = tid & 7;   // B staging: row 0..31, float4 idx

    for (int kc = 0; kc < C_; kc += BK) {
        float4 av0 = *(const float4*)(xT + (size_t)(m0 + ar) * C_ + kc + aq * 4);
        float4 av1 = *(const float4*)(xT + (size_t)(m0 + ar) * C_ + kc + (aq + 4) * 4);
        float4 bv[4];
#pragma unroll
        for (int s = 0; s < 4; ++s)
            bv[s] = *(const float4*)(Wx + (size_t)(kc + br) * G_ + n0 + (bq + 8 * s) * 4);

        __syncthreads();
        As[(aq * 4 + 0) * AS_STRIDE + ar] = av0.x;
        As[(aq * 4 + 1) * AS_STRIDE + ar] = av0.y;
        As[(aq * 4 + 2) * AS_STRIDE + ar] = av0.z;
        As[(aq * 4 + 3) * AS_STRIDE + ar] = av0.w;
        As[((aq + 4) * 4 + 0) * AS_STRIDE + ar] = av1.x;
        As[((aq + 4) * 4 + 1) * AS_STRIDE + ar] = av1.y;
        As[((aq + 4) * 4 + 2) * AS_STRIDE + ar] = av1.z;
        As[((aq + 4) * 4 + 3) * AS_STRIDE + ar] = av1.w;
#pragma unroll
        for (int s = 0; s < 4; ++s)
            *(float4*)&Bs[br * BS_STRIDE + (bq + 8 * s) * 4] = bv[s];
        __syncthreads();

#pragma unroll
        for (int k = 0; k < BK; ++k) {
            float4 a0 = *(const float4*)&As[k * AS_STRIDE + tm];
            float4 a1 = *(const float4*)&As[k * AS_STRIDE + tm + 4];
            float4 b0 = *(const float4*)&Bs[k * BS_STRIDE + tn4];
            float am[8] = {a0.x, a0.y, a0.z, a0.w, a1.x, a1.y, a1.z, a1.w};
#pragma unroll
            for (int i = 0; i < 8; ++i) {
                acc[i].x += am[i] * b0.x;
                acc[i].y += am[i] * b0.y;
                acc[i].z += am[i] * b0.z;
                acc[i].w += am[i] * b0.w;
            }
        }
    }

    float4 bb = *(const float4*)(bias + n0 + tn4);
#pragma unroll
    for (int i = 0; i < 8; ++i) {
        float4 o;
        o.x = acc[i].x + bb.x; o.y = acc[i].y + bb.y;
        o.z = acc[i].z + bb.z; o.w = acc[i].w + bb.w;
        *(float4*)(xp + (size_t)(m0 + tm + i) * G_ + n0 + tn4) = o;
    }
}

// ---------------------------------------------------------------------------
// B: persistent wavefront scan. 512 blocks = 64 rows x 8 n-tiles, 640 thr.
// Release/acquire message passing:
//   producer: plain stores -> __syncthreads (drains vmcnt) -> fetch_add RELEASE
//   consumer: spin load ACQUIRE (cache-inv) -> barrier -> plain float4 loads
// ---------------------------------------------------------------------------
#define NT 32        // n per block
#define NC 160       // columns per block = 5*NT
#define GP_STRIDE 12 // [kq][c][b] padded b-dim

__global__ __launch_bounds__(640) void k_scan(const float* __restrict__ xp,
                                              const float* __restrict__ Wh1,
                                              const float* __restrict__ Wh2,
                                              float* __restrict__ hbuf,
                                              float* __restrict__ cbuf,
                                              unsigned int* __restrict__ flags) {
    __shared__ float hs[2][B_ * HID_];       // [0]=h_left, [1]=h_up; 16 KB
    __shared__ float gp[4 * NC * GP_STRIDE]; // 30 KB

    int w  = blockIdx.x >> 3;
    int nt = blockIdx.x & 7;
    int n0 = nt * NT;
    int tid = threadIdx.x;

    int kq4 = tid / NC;          // 0..3 combined-K quarter
    int c   = tid % NC;          // 0..159
    int gate = c >> 5, nn = c & 31;
    int j = gate * 256 + n0 + nn;
    const float* Wm = (kq4 < 2) ? Wh1 : Wh2;   // wave-uniform
    int sel = (kq4 < 2) ? 0 : 1;
    int kk0 = (kq4 & 1) * 128;

    for (int h = 0; h < H_; ++h) {
        int wh = w * H_ + h;

        if (tid == 0) {
            if (w > 0) {
                const unsigned int* f = &flags[wh - H_];
                while (__hip_atomic_load(f, __ATOMIC_ACQUIRE, __HIP_MEMORY_SCOPE_AGENT) < 8u)
                    __builtin_amdgcn_s_sleep(2);
            }
            if (h > 0) {
                const unsigned int* f = &flags[wh - 1];
                while (__hip_atomic_load(f, __ATOMIC_ACQUIRE, __HIP_MEMORY_SCOPE_AGENT) < 8u)
                    __builtin_amdgcn_s_sleep(2);
            }
        }
        __syncthreads();

        // stage h_left -> hs[0], h_up -> hs[1]; plain vectorized loads (fresh
        // after the acquire above); zeros at boundaries
        {
            const float4* pl = (const float4*)(hbuf + (size_t)(wh - 1) * CELL_STRIDE);
            const float4* pu = (const float4*)(hbuf + (size_t)(wh - H_) * CELL_STRIDE);
            float4 z; z.x = z.y = z.z = z.w = 0.f;
            for (int i = tid; i < 512; i += 640) {
                ((float4*)hs[0])[i] = (h > 0) ? pl[i] : z;
                ((float4*)hs[1])[i] = (w > 0) ? pu[i] : z;
            }
        }
        __syncthreads();

        float acc[8];
#pragma unroll
        for (int b = 0; b < 8; ++b) acc[b] = 0.f;

        for (int kk = kk0; kk < kk0 + 128; kk += 4) {
            float w0 = Wm[(size_t)(kk + 0) * G_ + j];
            float w1 = Wm[(size_t)(kk + 1) * G_ + j];
            float w2 = Wm[(size_t)(kk + 2) * G_ + j];
            float w3 = Wm[(size_t)(kk + 3) * G_ + j];
#pragma unroll
            for (int b = 0; b < 8; ++b) {
                float4 hv = *(const float4*)&hs[sel][b * HID_ + kk];  // broadcast
                acc[b] += hv.x * w0 + hv.y * w1 + hv.z * w2 + hv.w * w3;
            }
        }

        {
            float4 p0, p1;
            p0.x = acc[0]; p0.y = acc[1]; p0.z = acc[2]; p0.w = acc[3];
            p1.x = acc[4]; p1.y = acc[5]; p1.z = acc[6]; p1.w = acc[7];
            int base = (kq4 * NC + c) * GP_STRIDE;
            *(float4*)&gp[base] = p0;
            *(float4*)&gp[base + 4] = p1;
        }
        __syncthreads();

        // reduce 4 quarters + xp -> gp[c][b]
        for (int idx = tid; idx < NC * 8; idx += 640) {
            int b = idx / NC;
            int cc = idx % NC;
            float s = gp[(0 * NC + cc) * GP_STRIDE + b]
                    + gp[(1 * NC + cc) * GP_STRIDE + b]
                    + gp[(2 * NC + cc) * GP_STRIDE + b]
                    + gp[(3 * NC + cc) * GP_STRIDE + b];
            int g2 = cc >> 5, nn2 = cc & 31;
            int jj = g2 * 256 + n0 + nn2;
            s += xp[((size_t)wh * B_ + b) * G_ + jj];
            gp[cc * GP_STRIDE + b] = s;
        }
        __syncthreads();

        // cell update: 8 b x 32 n (plain stores; fresh cl/cu per acquire)
        if (tid < 256) {
            int b2 = tid >> 5, nn2 = tid & 31;
            int n = n0 + nn2;
            float iv = sigmoidf_(gp[(0 * 32 + nn2) * GP_STRIDE + b2]);
            float f1 = sigmoidf_(gp[(1 * 32 + nn2) * GP_STRIDE + b2]);
            float f2 = sigmoidf_(gp[(2 * 32 + nn2) * GP_STRIDE + b2]);
            float ov = sigmoidf_(gp[(3 * 32 + nn2) * GP_STRIDE + b2]);
            float cd = tanhf_(gp[(4 * 32 + nn2) * GP_STRIDE + b2]);
            float cl = (h > 0) ? cbuf[(size_t)(wh - 1) * CELL_STRIDE + b2 * HID_ + n] : 0.f;
            float cu = (w > 0) ? cbuf[(size_t)(wh - H_) * CELL_STRIDE + b2 * HID_ + n] : 0.f;
            float cv = iv * cd + f1 * cl + f2 * cu;
            float hh = ov * tanhf_(cv);
            cbuf[(size_t)wh * CELL_STRIDE + b2 * HID_ + n] = cv;
            hbuf[(size_t)wh * CELL_STRIDE + b2 * HID_ + n] = hh;
        }
        __syncthreads();  // barrier drains vmcnt: stores complete before release

        if (tid == 0)
            __hip_atomic_fetch_add(&flags[wh], 1u, __ATOMIC_RELEASE, __HIP_MEMORY_SCOPE_AGENT);
    }
}

// ---------------------------------------------------------------------------
// C1: BN partial stats (column sums over 16384 rows x 256 cols)
// ---------------------------------------------------------------------------
__global__ __launch_bounds__(256) void k_stats(const float* __restrict__ hbuf,
                                               float* __restrict__ ssum,
                                               float* __restrict__ ssq) {
    int t = threadIdx.x;
    size_t r0 = (size_t)blockIdx.x * 64;
    float s = 0.f, q = 0.f;
    for (int r = 0; r < 64; ++r) {
        float v = hbuf[(r0 + r) * HID_ + t];
        s += v; q += v * v;
    }
    atomicAdd(&ssum[t], s);
    atomicAdd(&ssq[t], q);
}

__global__ void k_finstats(const float* __restrict__ ssum, const float* __restrict__ ssq,
                           float* __restrict__ mean, float* __restrict__ rinv) {
    int t = threadIdx.x;
    const float inv_n = 1.0f / 16384.0f;
    float m = ssum[t] * inv_n;
    float v = ssq[t] * inv_n - m * m;
    mean[t] = m;
    rinv[t] = rsqrtf(v + 1e-5f);
}

// ---------------------------------------------------------------------------
// C2: transpose (wh,b,n) -> (b,n,wh); fused BN+tanh for out
// ---------------------------------------------------------------------------
__global__ __launch_bounds__(256) void k_out(const float* __restrict__ hbuf,
                                             const float* __restrict__ cbuf,
                                             const float* __restrict__ mean,
                                             const float* __restrict__ rinv,
                                             const float* __restrict__ gamma,
                                             const float* __restrict__ beta,
                                             float* __restrict__ outp) {
    __shared__ float tile[64][65];
    int bi = blockIdx.x;
    int b = bi >> 7;
    int rem = bi & 127;
    int wh0 = (rem >> 2) * 64;
    int n0 = (rem & 3) * 64;
    int xcol = threadIdx.x & 63;
    int yrow = threadIdx.x >> 6;

    float* out0   = outp;
    float* state0 = outp + (size_t)B_ * HID_ * WH_;
    float* cell0  = state0 + (size_t)B_ * HID_ * WH_;

    for (int yy = yrow; yy < 64; yy += 4)
        tile[yy][xcol] = hbuf[((size_t)(wh0 + yy) * B_ + b) * HID_ + n0 + xcol];
    __syncthreads();
    for (int yy = yrow; yy < 64; yy += 4) {
        int n = n0 + yy;
        float sv = tile[xcol][yy];
        size_t oidx = ((size_t)b * HID_ + n) * WH_ + wh0 + xcol;
        state0[oidx] = sv;
        float xn = (sv - mean[n]) * rinv[n];
        out0[oidx] = tanhf_(xn * gamma[n] + beta[n]);
    }
    __syncthreads();

    for (int yy = yrow; yy < 64; yy += 4)
        tile[yy][xcol] = cbuf[((size_t)(wh0 + yy) * B_ + b) * HID_ + n0 + xcol];
    __syncthreads();
    for (int yy = yrow; yy < 64; yy += 4) {
        int n = n0 + yy;
        size_t oidx = ((size_t)b * HID_ + n) * WH_ + wh0 + xcol;
        cell0[oidx] = tile[xcol][yy];
    }
}

// ---------------------------------------------------------------------------
extern "C" void kernel_launch(void* const* d_in, const int* in_sizes, int n_in,
                              void* d_out, int out_size, void* d_ws, size_t ws_size,
                              hipStream_t stream) {
    const float* x     = (const float*)d_in[0];
    const float* Wx    = (const float*)d_in[1];
    const float* Wh1   = (const float*)d_in[2];
    const float* Wh2   = (const float*)d_in[3];
    const float* bias  = (const float*)d_in[4];
    const float* gamma = (const float*)d_in[5];
    const float* beta  = (const float*)d_in[6];
    float* out = (float*)d_out;
    float* ws  = (float*)d_ws;

    float* xp   = ws;                       // 20,971,520 floats
    float* xT   = ws + 20971520;            // 8,388,608 floats (dead after xproj)
    float* hbuf = xT;                       // alias (4,194,304 floats)
    float* cbuf = xT + 4194304;             // alias (4,194,304 floats)
    float* ssum = ws + 29360128;
    float* ssq  = ssum + 256;
    float* mean = ssum + 512;
    float* rinv = ssum + 768;
    unsigned int* flags = (unsigned int*)(ws + 29361152);  // 2048 u32

    k_transpose_x<<<dim3(64, 32), 256, 0, stream>>>(x, xT);
    k_xproj<<<2560, 256, 0, stream>>>(xT, Wx, bias, xp);

    // zero ssum/ssq/mean/rinv + flags (3072 floats total); kernel-dispatch
    // acquire before k_scan guarantees visibility of the zeros.
    hipMemsetAsync(ssum, 0, 3072 * sizeof(float), stream);

    k_scan<<<512, 640, 0, stream>>>(xp, Wh1, Wh2, hbuf, cbuf, flags);

    k_stats<<<256, 256, 0, stream>>>(hbuf, ssum, ssq);
    k_finstats<<<1, 256, 0, stream>>>(ssum, ssq, mean, rinv);
    k_out<<<8 * 32 * 4, 256, 0, stream>>>(hbuf, cbuf, mean, rinv, gamma, beta, out);
}

// Round 5
// 1672.283 us; speedup vs baseline: 3.5657x; 3.5657x over previous
//
#include <hip/hip_runtime.h>
#include <math.h>

#define B_ 8
#define C_ 512
#define W_ 64
#define H_ 32
#define HID_ 256
#define G_ 1280
#define WH_ (W_*H_)           // 2048
#define CELL_STRIDE (B_*HID_) // 2048 floats per (w,h) cell in hbuf/cbuf

typedef float v4f __attribute__((ext_vector_type(4)));
typedef int   v4i __attribute__((ext_vector_type(4)));

__device__ __forceinline__ float sigmoidf_(float x) {
    return 1.0f / (1.0f + __expf(-x));
}

__device__ __forceinline__ float tanhf_(float x) {
    float ax = fabsf(x);
    float e = __expf(-2.0f * ax);
    float t = (1.0f - e) / (1.0f + e);
    return copysignf(t, x);
}

// ---- device-coherent (sc0 sc1: bypass L1+L2, ordered at IF) accessors ----
__device__ __forceinline__ v4f ldg_byp4(const float* p) {
    v4f r;
    asm volatile("global_load_dwordx4 %0, %1, off sc0 sc1\n\ts_waitcnt vmcnt(0)"
                 : "=v"(r) : "v"(p) : "memory");
    return r;
}
__device__ __forceinline__ void ldg_byp4x2(const float* p0, const float* p1,
                                           v4f& a, v4f& b) {
    asm volatile("global_load_dwordx4 %0, %2, off sc0 sc1\n\t"
                 "global_load_dwordx4 %1, %3, off sc0 sc1\n\t"
                 "s_waitcnt vmcnt(0)"
                 : "=&v"(a), "=&v"(b) : "v"(p0), "v"(p1) : "memory");
}
__device__ __forceinline__ float ldg_byp1(const float* p) {
    float r;
    asm volatile("global_load_dword %0, %1, off sc0 sc1\n\ts_waitcnt vmcnt(0)"
                 : "=v"(r) : "v"(p) : "memory");
    return r;
}
__device__ __forceinline__ void ldg_byp1x2(const float* p0, const float* p1,
                                           float& a, float& b) {
    asm volatile("global_load_dword %0, %2, off sc0 sc1\n\t"
                 "global_load_dword %1, %3, off sc0 sc1\n\t"
                 "s_waitcnt vmcnt(0)"
                 : "=&v"(a), "=&v"(b) : "v"(p0), "v"(p1) : "memory");
}
__device__ __forceinline__ void stg_byp1(float* p, float v) {
    asm volatile("global_store_dword %0, %1, off sc0 sc1" :: "v"(p), "v"(v) : "memory");
}
__device__ __forceinline__ void stg_byp_u32(unsigned* p, unsigned v) {
    asm volatile("global_store_dword %0, %1, off sc0 sc1" :: "v"(p), "v"(v) : "memory");
}
__device__ __forceinline__ int flags8_sum(const unsigned* p) {
    v4i a, b;
    asm volatile("global_load_dwordx4 %0, %2, off sc0 sc1\n\t"
                 "global_load_dwordx4 %1, %3, off sc0 sc1\n\t"
                 "s_waitcnt vmcnt(0)"
                 : "=&v"(a), "=&v"(b) : "v"(p), "v"(p + 4) : "memory");
    return a.x + a.y + a.z + a.w + b.x + b.y + b.z + b.w;
}
__device__ __forceinline__ void drain_stores() {
    asm volatile("s_waitcnt vmcnt(0)" ::: "memory");
}

// ---------------------------------------------------------------------------
// A0: transpose x (B,C,W,H) = [bc][wh] row-major  ->  xT [wh][bc]
// ---------------------------------------------------------------------------
__global__ __launch_bounds__(256) void k_transpose_x(const float* __restrict__ x,
                                                     float* __restrict__ xT) {
    __shared__ float tile[64][65];
    int bc0 = blockIdx.x * 64;
    int wh0 = blockIdx.y * 64;
    int xcol = threadIdx.x & 63;
    int yrow = threadIdx.x >> 6;
    for (int yy = yrow; yy < 64; yy += 4)
        tile[yy][xcol] = x[(size_t)(bc0 + yy) * WH_ + wh0 + xcol];
    __syncthreads();
    for (int yy = yrow; yy < 64; yy += 4)
        xT[(size_t)(wh0 + yy) * (B_*C_) + bc0 + xcol] = tile[xcol][yy];
}

// ---------------------------------------------------------------------------
// A: GEMM  xp[m][g] = sum_c A[m][c]*Wx[c][g] + bias[g],  m = wh*8+b (16384)
// BM=64, BN=128, BK=32; 256 threads; micro-tile 8m x 4n (row-contiguous stores)
// ---------------------------------------------------------------------------
#define BM 64
#define BN 128
#define BK 32
#define AS_STRIDE 68    // [k][m] padded
#define BS_STRIDE 132   // [k][n] padded

__global__ __launch_bounds__(256) void k_xproj(const float* __restrict__ xT,
                                               const float* __restrict__ Wx,
                                               const float* __restrict__ bias,
                                               float* __restrict__ xp) {
    __shared__ float As[BK * AS_STRIDE];
    __shared__ float Bs[BK * BS_STRIDE];

    int bid = blockIdx.x;
    int xcd = bid & 7;
    int slot = bid >> 3;             // 0..319
    int mt = xcd * 32 + slot / 10;   // 0..255
    int nt = slot % 10;              // 0..9
    int m0 = mt * BM, n0 = nt * BN;
    int tid = threadIdx.x;

    int tm  = (tid >> 5) * 8;        // 0..56 (8 rows per thread)
    int tn4 = (tid & 31) * 4;        // 0..124 (4 contiguous n per thread)

    float4 acc[8];
#pragma unroll
    for (int i = 0; i < 8; ++i) { acc[i].x = acc[i].y = acc[i].z = acc[i].w = 0.f; }

    int ar = tid >> 2, aq = tid & 3;   // A staging: row 0..63, float4 idx
    int br = tid >> 3, bq = tid & 7;   // B staging: row 0..31, float4 idx

    for (int kc = 0; kc < C_; kc += BK) {
        float4 av0 = *(const float4*)(xT + (size_t)(m0 + ar) * C_ + kc + aq * 4);
        float4 av1 = *(const float4*)(xT + (size_t)(m0 + ar) * C_ + kc + (aq + 4) * 4);
        float4 bv[4];
#pragma unroll
        for (int s = 0; s < 4; ++s)
            bv[s] = *(const float4*)(Wx + (size_t)(kc + br) * G_ + n0 + (bq + 8 * s) * 4);

        __syncthreads();
        As[(aq * 4 + 0) * AS_STRIDE + ar] = av0.x;
        As[(aq * 4 + 1) * AS_STRIDE + ar] = av0.y;
        As[(aq * 4 + 2) * AS_STRIDE + ar] = av0.z;
        As[(aq * 4 + 3) * AS_STRIDE + ar] = av0.w;
        As[((aq + 4) * 4 + 0) * AS_STRIDE + ar] = av1.x;
        As[((aq + 4) * 4 + 1) * AS_STRIDE + ar] = av1.y;
        As[((aq + 4) * 4 + 2) * AS_STRIDE + ar] = av1.z;
        As[((aq + 4) * 4 + 3) * AS_STRIDE + ar] = av1.w;
#pragma unroll
        for (int s = 0; s < 4; ++s)
            *(float4*)&Bs[br * BS_STRIDE + (bq + 8 * s) * 4] = bv[s];
        __syncthreads();

#pragma unroll
        for (int k = 0; k < BK; ++k) {
            float4 a0 = *(const float4*)&As[k * AS_STRIDE + tm];
            float4 a1 = *(const float4*)&As[k * AS_STRIDE + tm + 4];
            float4 b0 = *(const float4*)&Bs[k * BS_STRIDE + tn4];
            float am[8] = {a0.x, a0.y, a0.z, a0.w, a1.x, a1.y, a1.z, a1.w};
#pragma unroll
            for (int i = 0; i < 8; ++i) {
                acc[i].x += am[i] * b0.x;
                acc[i].y += am[i] * b0.y;
                acc[i].z += am[i] * b0.z;
                acc[i].w += am[i] * b0.w;
            }
        }
    }

    float4 bb = *(const float4*)(bias + n0 + tn4);
#pragma unroll
    for (int i = 0; i < 8; ++i) {
        float4 o;
        o.x = acc[i].x + bb.x; o.y = acc[i].y + bb.y;
        o.z = acc[i].z + bb.z; o.w = acc[i].w + bb.w;
        *(float4*)(xp + (size_t)(m0 + tm + i) * G_ + n0 + tn4) = o;
    }
}

// ---------------------------------------------------------------------------
// B: persistent wavefront scan. 512 blocks = 64 rows x 8 n-tiles, 640 thr.
// All cross-block traffic (h, c, flags) via sc0sc1 bypass ops (no cache
// maintenance). Producer: bypass stores -> vmcnt(0) -> barrier -> flag:=1.
// Consumer: spin on 8 flags (bypass dwordx4 x2) -> barrier -> bypass stage.
// Weights/xp use normal cached loads and stay L2-hot.
// ---------------------------------------------------------------------------
#define NT 32        // n per block
#define NC 160       // columns per block = 5*NT
#define GP_STRIDE 12 // [kq][c][b] padded b-dim

__global__ __launch_bounds__(640) void k_scan(const float* __restrict__ xp,
                                              const float* __restrict__ Wh1,
                                              const float* __restrict__ Wh2,
                                              float* __restrict__ hbuf,
                                              float* __restrict__ cbuf,
                                              unsigned int* __restrict__ flags) {
    __shared__ float hs[2][B_ * HID_];       // [0]=h_left, [1]=h_up; 16 KB
    __shared__ float gp[4 * NC * GP_STRIDE]; // 30 KB

    int w  = blockIdx.x >> 3;
    int nt = blockIdx.x & 7;
    int n0 = nt * NT;
    int tid = threadIdx.x;

    int kq4 = tid / NC;          // 0..3 combined-K quarter
    int c   = tid % NC;          // 0..159
    int gate = c >> 5, nn = c & 31;
    int j = gate * 256 + n0 + nn;
    const float* Wm = (kq4 < 2) ? Wh1 : Wh2;
    int sel = (kq4 < 2) ? 0 : 1;
    int kk0 = (kq4 & 1) * 128;

    for (int h = 0; h < H_; ++h) {
        int wh = w * H_ + h;

        if (tid == 0) {
            if (w > 0)
                while (flags8_sum(flags + (size_t)(wh - H_) * 8) != 8)
                    __builtin_amdgcn_s_sleep(4);
            if (h > 0)
                while (flags8_sum(flags + (size_t)(wh - 1) * 8) != 8)
                    __builtin_amdgcn_s_sleep(4);
        }
        __syncthreads();

        // stage h_left -> hs[0], h_up -> hs[1] via bypass loads; zeros at edges
        {
            const float* pl = hbuf + (size_t)(wh - 1) * CELL_STRIDE;
            const float* pu = hbuf + (size_t)(wh - H_) * CELL_STRIDE;
            for (int i = tid; i < 512; i += 640) {
                v4f vl, vu;
                if (h > 0 && w > 0) {
                    ldg_byp4x2(pl + i * 4, pu + i * 4, vl, vu);
                } else {
                    vl = 0.f; vu = 0.f;
                    if (h > 0) vl = ldg_byp4(pl + i * 4);
                    if (w > 0) vu = ldg_byp4(pu + i * 4);
                }
                *(v4f*)&hs[0][i * 4] = vl;
                *(v4f*)&hs[1][i * 4] = vu;
            }
        }
        __syncthreads();

        float acc[8];
#pragma unroll
        for (int b = 0; b < 8; ++b) acc[b] = 0.f;

        for (int kk = kk0; kk < kk0 + 128; kk += 4) {
            float w0 = Wm[(size_t)(kk + 0) * G_ + j];
            float w1 = Wm[(size_t)(kk + 1) * G_ + j];
            float w2 = Wm[(size_t)(kk + 2) * G_ + j];
            float w3 = Wm[(size_t)(kk + 3) * G_ + j];
#pragma unroll
            for (int b = 0; b < 8; ++b) {
                float4 hv = *(const float4*)&hs[sel][b * HID_ + kk];  // broadcast
                acc[b] += hv.x * w0 + hv.y * w1 + hv.z * w2 + hv.w * w3;
            }
        }

        {
            float4 p0, p1;
            p0.x = acc[0]; p0.y = acc[1]; p0.z = acc[2]; p0.w = acc[3];
            p1.x = acc[4]; p1.y = acc[5]; p1.z = acc[6]; p1.w = acc[7];
            int base = (kq4 * NC + c) * GP_STRIDE;
            *(float4*)&gp[base] = p0;
            *(float4*)&gp[base + 4] = p1;
        }
        __syncthreads();

        // reduce 4 quarters + xp -> gp[c][b]   (xp: normal cached loads)
        for (int idx = tid; idx < NC * 8; idx += 640) {
            int b = idx / NC;
            int cc = idx % NC;
            float s = gp[(0 * NC + cc) * GP_STRIDE + b]
                    + gp[(1 * NC + cc) * GP_STRIDE + b]
                    + gp[(2 * NC + cc) * GP_STRIDE + b]
                    + gp[(3 * NC + cc) * GP_STRIDE + b];
            int g2 = cc >> 5, nn2 = cc & 31;
            int jj = g2 * 256 + n0 + nn2;
            s += xp[((size_t)wh * B_ + b) * G_ + jj];
            gp[cc * GP_STRIDE + b] = s;
        }
        __syncthreads();

        // cell update: 8 b x 32 n; c-neighbors and outputs via bypass ops
        if (tid < 256) {
            int b2 = tid >> 5, nn2 = tid & 31;
            int n = n0 + nn2;
            float iv = sigmoidf_(gp[(0 * 32 + nn2) * GP_STRIDE + b2]);
            float f1 = sigmoidf_(gp[(1 * 32 + nn2) * GP_STRIDE + b2]);
            float f2 = sigmoidf_(gp[(2 * 32 + nn2) * GP_STRIDE + b2]);
            float ov = sigmoidf_(gp[(3 * 32 + nn2) * GP_STRIDE + b2]);
            float cd = tanhf_(gp[(4 * 32 + nn2) * GP_STRIDE + b2]);
            float cl = 0.f, cu = 0.f;
            const float* pcl = cbuf + (size_t)(wh - 1) * CELL_STRIDE + b2 * HID_ + n;
            const float* pcu = cbuf + (size_t)(wh - H_) * CELL_STRIDE + b2 * HID_ + n;
            if (h > 0 && w > 0) ldg_byp1x2(pcl, pcu, cl, cu);
            else if (h > 0) cl = ldg_byp1(pcl);
            else if (w > 0) cu = ldg_byp1(pcu);
            float cv = iv * cd + f1 * cl + f2 * cu;
            float hh = ov * tanhf_(cv);
            stg_byp1(cbuf + (size_t)wh * CELL_STRIDE + b2 * HID_ + n, cv);
            stg_byp1(hbuf + (size_t)wh * CELL_STRIDE + b2 * HID_ + n, hh);
        }
        drain_stores();     // per-wave: data stores at coherence point
        __syncthreads();    // all waves drained before flag

        if (tid == 0)
            stg_byp_u32(&flags[(size_t)wh * 8 + nt], 1u);
    }
}

// ---------------------------------------------------------------------------
// C1: BN partial stats (column sums over 16384 rows x 256 cols)
// ---------------------------------------------------------------------------
__global__ __launch_bounds__(256) void k_stats(const float* __restrict__ hbuf,
                                               float* __restrict__ ssum,
                                               float* __restrict__ ssq) {
    int t = threadIdx.x;
    size_t r0 = (size_t)blockIdx.x * 64;
    float s = 0.f, q = 0.f;
    for (int r = 0; r < 64; ++r) {
        float v = hbuf[(r0 + r) * HID_ + t];
        s += v; q += v * v;
    }
    atomicAdd(&ssum[t], s);
    atomicAdd(&ssq[t], q);
}

__global__ void k_finstats(const float* __restrict__ ssum, const float* __restrict__ ssq,
                           float* __restrict__ mean, float* __restrict__ rinv) {
    int t = threadIdx.x;
    const float inv_n = 1.0f / 16384.0f;
    float m = ssum[t] * inv_n;
    float v = ssq[t] * inv_n - m * m;
    mean[t] = m;
    rinv[t] = rsqrtf(v + 1e-5f);
}

// ---------------------------------------------------------------------------
// C2: transpose (wh,b,n) -> (b,n,wh); fused BN+tanh for out
// ---------------------------------------------------------------------------
__global__ __launch_bounds__(256) void k_out(const float* __restrict__ hbuf,
                                             const float* __restrict__ cbuf,
                                             const float* __restrict__ mean,
                                             const float* __restrict__ rinv,
                                             const float* __restrict__ gamma,
                                             const float* __restrict__ beta,
                                             float* __restrict__ outp) {
    __shared__ float tile[64][65];
    int bi = blockIdx.x;
    int b = bi >> 7;
    int rem = bi & 127;
    int wh0 = (rem >> 2) * 64;
    int n0 = (rem & 3) * 64;
    int xcol = threadIdx.x & 63;
    int yrow = threadIdx.x >> 6;

    float* out0   = outp;
    float* state0 = outp + (size_t)B_ * HID_ * WH_;
    float* cell0  = state0 + (size_t)B_ * HID_ * WH_;

    for (int yy = yrow; yy < 64; yy += 4)
        tile[yy][xcol] = hbuf[((size_t)(wh0 + yy) * B_ + b) * HID_ + n0 + xcol];
    __syncthreads();
    for (int yy = yrow; yy < 64; yy += 4) {
        int n = n0 + yy;
        float sv = tile[xcol][yy];
        size_t oidx = ((size_t)b * HID_ + n) * WH_ + wh0 + xcol;
        state0[oidx] = sv;
        float xn = (sv - mean[n]) * rinv[n];
        out0[oidx] = tanhf_(xn * gamma[n] + beta[n]);
    }
    __syncthreads();

    for (int yy = yrow; yy < 64; yy += 4)
        tile[yy][xcol] = cbuf[((size_t)(wh0 + yy) * B_ + b) * HID_ + n0 + xcol];
    __syncthreads();
    for (int yy = yrow; yy < 64; yy += 4) {
        int n = n0 + yy;
        size_t oidx = ((size_t)b * HID_ + n) * WH_ + wh0 + xcol;
        cell0[oidx] = tile[xcol][yy];
    }
}

// ---------------------------------------------------------------------------
extern "C" void kernel_launch(void* const* d_in, const int* in_sizes, int n_in,
                              void* d_out, int out_size, void* d_ws, size_t ws_size,
                              hipStream_t stream) {
    const float* x     = (const float*)d_in[0];
    const float* Wx    = (const float*)d_in[1];
    const float* Wh1   = (const float*)d_in[2];
    const float* Wh2   = (const float*)d_in[3];
    const float* bias  = (const float*)d_in[4];
    const float* gamma = (const float*)d_in[5];
    const float* beta  = (const float*)d_in[6];
    float* out = (float*)d_out;
    float* ws  = (float*)d_ws;

    float* xp   = ws;                       // 20,971,520 floats
    float* xT   = ws + 20971520;            // 8,388,608 floats (dead after xproj)
    float* hbuf = xT;                       // alias (4,194,304 floats)
    float* cbuf = xT + 4194304;             // alias (4,194,304 floats)
    float* ssum = ws + 29360128;
    float* ssq  = ssum + 256;
    float* mean = ssum + 512;
    float* rinv = ssum + 768;
    unsigned int* flags = (unsigned int*)(ws + 29361152);  // 2048*8 u32 (64 KB)

    k_transpose_x<<<dim3(64, 32), 256, 0, stream>>>(x, xT);
    k_xproj<<<2560, 256, 0, stream>>>(xT, Wx, bias, xp);

    // zero stats (1024 floats) + flags (16384 u32)
    hipMemsetAsync(ssum, 0, (1024 + 16384) * sizeof(unsigned int), stream);

    k_scan<<<512, 640, 0, stream>>>(xp, Wh1, Wh2, hbuf, cbuf, flags);

    k_stats<<<256, 256, 0, stream>>>(hbuf, ssum, ssq);
    k_finstats<<<1, 256, 0, stream>>>(ssum, ssq, mean, rinv);
    k_out<<<8 * 32 * 4, 256, 0, stream>>>(hbuf, cbuf, mean, rinv, gamma, beta, out);
}

// Round 6
// 1297.640 us; speedup vs baseline: 4.5951x; 1.2887x over previous
//
#include <hip/hip_runtime.h>
#include <math.h>

#define B_ 8
#define C_ 512
#define W_ 64
#define H_ 32
#define HID_ 256
#define G_ 1280
#define WH_ (W_*H_)           // 2048
#define CELL_STRIDE (B_*HID_) // 2048 floats per (w,h) cell in hbuf/cbuf

typedef float v4f __attribute__((ext_vector_type(4)));

__device__ __forceinline__ float sigmoidf_(float x) {
    return 1.0f / (1.0f + __expf(-x));
}

__device__ __forceinline__ float tanhf_(float x) {
    float ax = fabsf(x);
    float e = __expf(-2.0f * ax);
    float t = (1.0f - e) / (1.0f + e);
    return copysignf(t, x);
}

// ---- device-coherent (sc0 sc1: bypass L1+L2, served at coherence point) ----
__device__ __forceinline__ unsigned ldg_byp_u32v(const unsigned* p) {
    unsigned r;
    asm volatile("global_load_dword %0, %1, off sc0 sc1\n\ts_waitcnt vmcnt(0)"
                 : "=v"(r) : "v"(p) : "memory");
    return r;
}
__device__ __forceinline__ void stg_byp1(float* p, float v) {
    asm volatile("global_store_dword %0, %1, off sc0 sc1" :: "v"(p), "v"(v) : "memory");
}
__device__ __forceinline__ void stg_byp_u32(unsigned* p, unsigned v) {
    asm volatile("global_store_dword %0, %1, off sc0 sc1" :: "v"(p), "v"(v) : "memory");
}
__device__ __forceinline__ void drain_stores() {
    asm volatile("s_waitcnt vmcnt(0)" ::: "memory");
}
// batched stage: 4x dwordx4 (h_left x2, h_up x2) + 2x dword (c_l, c_u), 1 wait
__device__ __forceinline__ void stage6(const float* pl0, const float* pl1,
                                       const float* pu0, const float* pu1,
                                       const float* pc0, const float* pc1,
                                       v4f& l0, v4f& l1, v4f& u0, v4f& u1,
                                       float& cl, float& cu) {
    asm volatile(
        "global_load_dwordx4 %0, %6, off sc0 sc1\n\t"
        "global_load_dwordx4 %1, %7, off sc0 sc1\n\t"
        "global_load_dwordx4 %2, %8, off sc0 sc1\n\t"
        "global_load_dwordx4 %3, %9, off sc0 sc1\n\t"
        "global_load_dword %4, %10, off sc0 sc1\n\t"
        "global_load_dword %5, %11, off sc0 sc1\n\t"
        "s_waitcnt vmcnt(0)"
        : "=&v"(l0), "=&v"(l1), "=&v"(u0), "=&v"(u1), "=&v"(cl), "=&v"(cu)
        : "v"(pl0), "v"(pl1), "v"(pu0), "v"(pu1), "v"(pc0), "v"(pc1)
        : "memory");
}

// ---------------------------------------------------------------------------
// A0: transpose x (B,C,W,H) = [bc][wh] row-major  ->  xT [wh][bc]
// ---------------------------------------------------------------------------
__global__ __launch_bounds__(256) void k_transpose_x(const float* __restrict__ x,
                                                     float* __restrict__ xT) {
    __shared__ float tile[64][65];
    int bc0 = blockIdx.x * 64;
    int wh0 = blockIdx.y * 64;
    int xcol = threadIdx.x & 63;
    int yrow = threadIdx.x >> 6;
    for (int yy = yrow; yy < 64; yy += 4)
        tile[yy][xcol] = x[(size_t)(bc0 + yy) * WH_ + wh0 + xcol];
    __syncthreads();
    for (int yy = yrow; yy < 64; yy += 4)
        xT[(size_t)(wh0 + yy) * (B_*C_) + bc0 + xcol] = tile[xcol][yy];
}

// ---------------------------------------------------------------------------
// A: GEMM  xp[m][g] = sum_c A[m][c]*Wx[c][g] + bias[g],  m = wh*8+b (16384)
// BM=64, BN=128, BK=32; 256 threads; micro-tile 8m x 4n
// ---------------------------------------------------------------------------
#define BM 64
#define BN 128
#define BK 32
#define AS_STRIDE 68
#define BS_STRIDE 132

__global__ __launch_bounds__(256) void k_xproj(const float* __restrict__ xT,
                                               const float* __restrict__ Wx,
                                               const float* __restrict__ bias,
                                               float* __restrict__ xp) {
    __shared__ float As[BK * AS_STRIDE];
    __shared__ float Bs[BK * BS_STRIDE];

    int bid = blockIdx.x;
    int xcd = bid & 7;
    int slot = bid >> 3;
    int mt = xcd * 32 + slot / 10;
    int nt = slot % 10;
    int m0 = mt * BM, n0 = nt * BN;
    int tid = threadIdx.x;

    int tm  = (tid >> 5) * 8;
    int tn4 = (tid & 31) * 4;

    float4 acc[8];
#pragma unroll
    for (int i = 0; i < 8; ++i) { acc[i].x = acc[i].y = acc[i].z = acc[i].w = 0.f; }

    int ar = tid >> 2, aq = tid & 3;
    int br = tid >> 3, bq = tid & 7;

    for (int kc = 0; kc < C_; kc += BK) {
        float4 av0 = *(const float4*)(xT + (size_t)(m0 + ar) * C_ + kc + aq * 4);
        float4 av1 = *(const float4*)(xT + (size_t)(m0 + ar) * C_ + kc + (aq + 4) * 4);
        float4 bv[4];
#pragma unroll
        for (int s = 0; s < 4; ++s)
            bv[s] = *(const float4*)(Wx + (size_t)(kc + br) * G_ + n0 + (bq + 8 * s) * 4);

        __syncthreads();
        As[(aq * 4 + 0) * AS_STRIDE + ar] = av0.x;
        As[(aq * 4 + 1) * AS_STRIDE + ar] = av0.y;
        As[(aq * 4 + 2) * AS_STRIDE + ar] = av0.z;
        As[(aq * 4 + 3) * AS_STRIDE + ar] = av0.w;
        As[((aq + 4) * 4 + 0) * AS_STRIDE + ar] = av1.x;
        As[((aq + 4) * 4 + 1) * AS_STRIDE + ar] = av1.y;
        As[((aq + 4) * 4 + 2) * AS_STRIDE + ar] = av1.z;
        As[((aq + 4) * 4 + 3) * AS_STRIDE + ar] = av1.w;
#pragma unroll
        for (int s = 0; s < 4; ++s)
            *(float4*)&Bs[br * BS_STRIDE + (bq + 8 * s) * 4] = bv[s];
        __syncthreads();

#pragma unroll
        for (int k = 0; k < BK; ++k) {
            float4 a0 = *(const float4*)&As[k * AS_STRIDE + tm];
            float4 a1 = *(const float4*)&As[k * AS_STRIDE + tm + 4];
            float4 b0 = *(const float4*)&Bs[k * BS_STRIDE + tn4];
            float am[8] = {a0.x, a0.y, a0.z, a0.w, a1.x, a1.y, a1.z, a1.w};
#pragma unroll
            for (int i = 0; i < 8; ++i) {
                acc[i].x += am[i] * b0.x;
                acc[i].y += am[i] * b0.y;
                acc[i].z += am[i] * b0.z;
                acc[i].w += am[i] * b0.w;
            }
        }
    }

    float4 bb = *(const float4*)(bias + n0 + tn4);
#pragma unroll
    for (int i = 0; i < 8; ++i) {
        float4 o;
        o.x = acc[i].x + bb.x; o.y = acc[i].y + bb.y;
        o.z = acc[i].z + bb.z; o.w = acc[i].w + bb.w;
        *(float4*)(xp + (size_t)(m0 + tm + i) * G_ + n0 + tn4) = o;
    }
}

// ---------------------------------------------------------------------------
// B: persistent wavefront scan. 512 blocks = 64 rows x 8 n-tiles, 256 thr.
// thread = (kq = tid>>5: K-slice of 64 of combined 512, c0 = tid&31),
// owns 5 gate-columns (g*256 + n0 + c0) for all 8 batches.
// LDS reads per step: 512 wave-insts (5x fewer than r5 -- the r5 bottleneck).
// Cross-block h/c/flags via sc0sc1 bypass (r5 protocol, proven).
// ---------------------------------------------------------------------------
#define NT 32
#define GP_B_STRIDE 1288   // 8*160 + 8 pad

__global__ __launch_bounds__(256, 2) void k_scan(const float* __restrict__ xp,
                                                 const float* __restrict__ Wh1,
                                                 const float* __restrict__ Wh2,
                                                 float* __restrict__ hbuf,
                                                 float* __restrict__ cbuf,
                                                 unsigned int* __restrict__ flags) {
    __shared__ float hs[2][B_ * HID_];        // [0]=h_left, [1]=h_up; 16 KB
    __shared__ float gp[B_ * GP_B_STRIDE];    // partials [b][kq][c]; 41 KB

    int w  = blockIdx.x >> 3;
    int nt = blockIdx.x & 7;
    int n0 = nt * NT;
    int tid = threadIdx.x;

    int kq  = tid >> 5;           // 0..7 (K-slice of 64 in combined 512)
    int c0  = tid & 31;           // n-column within tile
    int sel = kq >> 2;            // 0: Wh1/h_left, 1: Wh2/h_up  (wave-uniform)
    int kk0 = (kq & 3) * 64;
    const float* Wm = sel ? Wh2 : Wh1;
    const float* wbase = Wm + (size_t)kk0 * G_ + n0 + c0;
    const float* hbase = &hs[sel][0];

    int b2 = tid >> 5, nn2 = tid & 31;   // update-phase mapping (all 256 thr)

    for (int h = 0; h < H_; ++h) {
        int wh = w * H_ + h;

        // ---- poll producer flags (wave 0: 16 lanes in parallel) ----
        if (tid < 64) {
            const unsigned* fp = nullptr;
            if (tid < 8) { if (w > 0) fp = flags + (size_t)(wh - H_) * 8 + tid; }
            else if (tid < 16) { if (h > 0) fp = flags + (size_t)(wh - 1) * 8 + (tid - 8); }
            bool pending = (fp != nullptr);
            for (;;) {
                if (pending && ldg_byp_u32v(fp) != 0) pending = false;
                if (__ballot(pending) == 0) break;
                __builtin_amdgcn_s_sleep(1);
            }
        }
        __syncthreads();

        // ---- stage h_left, h_up (+ prefetch c_l, c_u) : one vmcnt round ----
        float cl, cu;
        {
            bool vl = (h > 0), vu = (w > 0);
            const float* pl_base = hbuf + (size_t)(wh - 1) * CELL_STRIDE;
            const float* pu_base = hbuf + (size_t)(wh - H_) * CELL_STRIDE;
            const float* pl0 = vl ? pl_base + tid * 4 : hbuf;
            const float* pl1 = vl ? pl_base + (tid + 256) * 4 : hbuf;
            const float* pu0 = vu ? pu_base + tid * 4 : hbuf;
            const float* pu1 = vu ? pu_base + (tid + 256) * 4 : hbuf;
            const float* pcl = vl ? cbuf + (size_t)(wh - 1) * CELL_STRIDE + b2 * HID_ + n0 + nn2 : cbuf;
            const float* pcu = vu ? cbuf + (size_t)(wh - H_) * CELL_STRIDE + b2 * HID_ + n0 + nn2 : cbuf;
            v4f l0, l1, u0, u1;
            stage6(pl0, pl1, pu0, pu1, pcl, pcu, l0, l1, u0, u1, cl, cu);
            if (!vl) { l0 = 0.f; l1 = 0.f; cl = 0.f; }
            if (!vu) { u0 = 0.f; u1 = 0.f; cu = 0.f; }
            ((v4f*)hs[0])[tid] = l0;
            ((v4f*)hs[0])[tid + 256] = l1;
            ((v4f*)hs[1])[tid] = u0;
            ((v4f*)hs[1])[tid + 256] = u1;
        }
        __syncthreads();

        // ---- GEMM: 5 gate-cols x 8 batches over K-slice of 64 ----
        float2 acc[5][8];
#pragma unroll
        for (int g = 0; g < 5; ++g)
#pragma unroll
            for (int b = 0; b < 8; ++b) acc[g][b] = make_float2(0.f, 0.f);

        for (int it = 0; it < 16; ++it) {
            int kk = kk0 + it * 4;
            const float* wp = wbase + (size_t)it * 4 * G_;
            float2 w01[5], w23[5];
#pragma unroll
            for (int g = 0; g < 5; ++g) {
                w01[g] = make_float2(wp[0 * (size_t)G_ + g * 256], wp[1 * (size_t)G_ + g * 256]);
                w23[g] = make_float2(wp[2 * (size_t)G_ + g * 256], wp[3 * (size_t)G_ + g * 256]);
            }
#pragma unroll
            for (int b = 0; b < 8; ++b) {
                float4 hv = *(const float4*)&hbase[b * HID_ + kk];   // broadcast
                float2 h01 = make_float2(hv.x, hv.y);
                float2 h23 = make_float2(hv.z, hv.w);
#pragma unroll
                for (int g = 0; g < 5; ++g) {
                    acc[g][b] += h01 * w01[g];   // -> v_pk_fma_f32
                    acc[g][b] += h23 * w23[g];
                }
            }
        }

        // write partials: gp[b][kq][c], lane-consecutive c -> conflict-free
#pragma unroll
        for (int g = 0; g < 5; ++g)
#pragma unroll
            for (int b = 0; b < 8; ++b)
                gp[b * GP_B_STRIDE + kq * 160 + g * 32 + c0] = acc[g][b].x + acc[g][b].y;
        __syncthreads();

        // ---- reduce 8 K-slices + xp -> fin (= hs[0], safe after barrier) ----
        float* fin = hs[0];
        for (int t = 0; t < 5; ++t) {
            int idx = tid + 256 * t;
            int b = idx / 160;
            int cc = idx - b * 160;
            float s = 0.f;
#pragma unroll
            for (int q = 0; q < 8; ++q) s += gp[b * GP_B_STRIDE + q * 160 + cc];
            int jj = (cc >> 5) * 256 + n0 + (cc & 31);
            s += xp[((size_t)wh * B_ + b) * G_ + jj];
            fin[b * 160 + cc] = s;
        }
        __syncthreads();

        // ---- cell update (all 256 threads; cl/cu prefetched) ----
        {
            float iv = sigmoidf_(fin[b2 * 160 + 0 * 32 + nn2]);
            float f1 = sigmoidf_(fin[b2 * 160 + 1 * 32 + nn2]);
            float f2 = sigmoidf_(fin[b2 * 160 + 2 * 32 + nn2]);
            float ov = sigmoidf_(fin[b2 * 160 + 3 * 32 + nn2]);
            float cd = tanhf_(fin[b2 * 160 + 4 * 32 + nn2]);
            float cv = iv * cd + f1 * cl + f2 * cu;
            float hh = ov * tanhf_(cv);
            int n = n0 + nn2;
            stg_byp1(cbuf + (size_t)wh * CELL_STRIDE + b2 * HID_ + n, cv);
            stg_byp1(hbuf + (size_t)wh * CELL_STRIDE + b2 * HID_ + n, hh);
        }
        drain_stores();     // per-thread stores retired at coherence point
        __syncthreads();    // all threads drained before flag

        if (tid == 0)
            stg_byp_u32(&flags[(size_t)wh * 8 + nt], 1u);
    }
}

// ---------------------------------------------------------------------------
// C1: BN partial stats
// ---------------------------------------------------------------------------
__global__ __launch_bounds__(256) void k_stats(const float* __restrict__ hbuf,
                                               float* __restrict__ ssum,
                                               float* __restrict__ ssq) {
    int t = threadIdx.x;
    size_t r0 = (size_t)blockIdx.x * 64;
    float s = 0.f, q = 0.f;
    for (int r = 0; r < 64; ++r) {
        float v = hbuf[(r0 + r) * HID_ + t];
        s += v; q += v * v;
    }
    atomicAdd(&ssum[t], s);
    atomicAdd(&ssq[t], q);
}

__global__ void k_finstats(const float* __restrict__ ssum, const float* __restrict__ ssq,
                           float* __restrict__ mean, float* __restrict__ rinv) {
    int t = threadIdx.x;
    const float inv_n = 1.0f / 16384.0f;
    float m = ssum[t] * inv_n;
    float v = ssq[t] * inv_n - m * m;
    mean[t] = m;
    rinv[t] = rsqrtf(v + 1e-5f);
}

// ---------------------------------------------------------------------------
// C2: transpose (wh,b,n) -> (b,n,wh); fused BN+tanh for out
// ---------------------------------------------------------------------------
__global__ __launch_bounds__(256) void k_out(const float* __restrict__ hbuf,
                                             const float* __restrict__ cbuf,
                                             const float* __restrict__ mean,
                                             const float* __restrict__ rinv,
                                             const float* __restrict__ gamma,
                                             const float* __restrict__ beta,
                                             float* __restrict__ outp) {
    __shared__ float tile[64][65];
    int bi = blockIdx.x;
    int b = bi >> 7;
    int rem = bi & 127;
    int wh0 = (rem >> 2) * 64;
    int n0 = (rem & 3) * 64;
    int xcol = threadIdx.x & 63;
    int yrow = threadIdx.x >> 6;

    float* out0   = outp;
    float* state0 = outp + (size_t)B_ * HID_ * WH_;
    float* cell0  = state0 + (size_t)B_ * HID_ * WH_;

    for (int yy = yrow; yy < 64; yy += 4)
        tile[yy][xcol] = hbuf[((size_t)(wh0 + yy) * B_ + b) * HID_ + n0 + xcol];
    __syncthreads();
    for (int yy = yrow; yy < 64; yy += 4) {
        int n = n0 + yy;
        float sv = tile[xcol][yy];
        size_t oidx = ((size_t)b * HID_ + n) * WH_ + wh0 + xcol;
        state0[oidx] = sv;
        float xn = (sv - mean[n]) * rinv[n];
        out0[oidx] = tanhf_(xn * gamma[n] + beta[n]);
    }
    __syncthreads();

    for (int yy = yrow; yy < 64; yy += 4)
        tile[yy][xcol] = cbuf[((size_t)(wh0 + yy) * B_ + b) * HID_ + n0 + xcol];
    __syncthreads();
    for (int yy = yrow; yy < 64; yy += 4) {
        int n = n0 + yy;
        size_t oidx = ((size_t)b * HID_ + n) * WH_ + wh0 + xcol;
        cell0[oidx] = tile[xcol][yy];
    }
}

// ---------------------------------------------------------------------------
extern "C" void kernel_launch(void* const* d_in, const int* in_sizes, int n_in,
                              void* d_out, int out_size, void* d_ws, size_t ws_size,
                              hipStream_t stream) {
    const float* x     = (const float*)d_in[0];
    const float* Wx    = (const float*)d_in[1];
    const float* Wh1   = (const float*)d_in[2];
    const float* Wh2   = (const float*)d_in[3];
    const float* bias  = (const float*)d_in[4];
    const float* gamma = (const float*)d_in[5];
    const float* beta  = (const float*)d_in[6];
    float* out = (float*)d_out;
    float* ws  = (float*)d_ws;

    float* xp   = ws;                       // 20,971,520 floats
    float* xT   = ws + 20971520;            // 8,388,608 floats (dead after xproj)
    float* hbuf = xT;                       // alias
    float* cbuf = xT + 4194304;             // alias
    float* ssum = ws + 29360128;
    float* ssq  = ssum + 256;
    float* mean = ssum + 512;
    float* rinv = ssum + 768;
    unsigned int* flags = (unsigned int*)(ws + 29361152);  // 16384 u32

    k_transpose_x<<<dim3(64, 32), 256, 0, stream>>>(x, xT);
    k_xproj<<<2560, 256, 0, stream>>>(xT, Wx, bias, xp);

    hipMemsetAsync(ssum, 0, (1024 + 16384) * sizeof(unsigned int), stream);

    k_scan<<<512, 256, 0, stream>>>(xp, Wh1, Wh2, hbuf, cbuf, flags);

    k_stats<<<256, 256, 0, stream>>>(hbuf, ssum, ssq);
    k_finstats<<<1, 256, 0, stream>>>(ssum, ssq, mean, rinv);
    k_out<<<8 * 32 * 4, 256, 0, stream>>>(hbuf, cbuf, mean, rinv, gamma, beta, out);
}

// Round 7
// 1074.894 us; speedup vs baseline: 5.5473x; 1.2072x over previous
//
#include <hip/hip_runtime.h>
#include <math.h>

#define B_ 8
#define C_ 512
#define W_ 64
#define H_ 32
#define HID_ 256
#define G_ 1280
#define WH_ (W_*H_)           // 2048
#define CELL_STRIDE (B_*HID_) // 2048 floats per (w,h) cell in hbuf/cbuf

typedef float v4f __attribute__((ext_vector_type(4)));

__device__ __forceinline__ float sigmoidf_(float x) {
    return 1.0f / (1.0f + __expf(-x));
}

__device__ __forceinline__ float tanhf_(float x) {
    float ax = fabsf(x);
    float e = __expf(-2.0f * ax);
    float t = (1.0f - e) / (1.0f + e);
    return copysignf(t, x);
}

// ---- device-coherent (sc0 sc1: bypass L1+L2, served at coherence point) ----
__device__ __forceinline__ unsigned ldg_byp_u32v(const unsigned* p) {
    unsigned r;
    asm volatile("global_load_dword %0, %1, off sc0 sc1\n\ts_waitcnt vmcnt(0)"
                 : "=v"(r) : "v"(p) : "memory");
    return r;
}
__device__ __forceinline__ void stg_byp1(float* p, float v) {
    asm volatile("global_store_dword %0, %1, off sc0 sc1" :: "v"(p), "v"(v) : "memory");
}
__device__ __forceinline__ void stg_byp_u32(unsigned* p, unsigned v) {
    asm volatile("global_store_dword %0, %1, off sc0 sc1" :: "v"(p), "v"(v) : "memory");
}
__device__ __forceinline__ void drain_stores() {
    asm volatile("s_waitcnt vmcnt(0)" ::: "memory");
}
// batched stage: 2x dwordx4 (h_left, h_up) + 2x dword (c_l, c_u), one wait
__device__ __forceinline__ void stage4(const float* pl, const float* pu,
                                       const float* pc0, const float* pc1,
                                       v4f& l0, v4f& u0, float& cl, float& cu) {
    asm volatile(
        "global_load_dwordx4 %0, %4, off sc0 sc1\n\t"
        "global_load_dwordx4 %1, %5, off sc0 sc1\n\t"
        "global_load_dword %2, %6, off sc0 sc1\n\t"
        "global_load_dword %3, %7, off sc0 sc1\n\t"
        "s_waitcnt vmcnt(0)"
        : "=&v"(l0), "=&v"(u0), "=&v"(cl), "=&v"(cu)
        : "v"(pl), "v"(pu), "v"(pc0), "v"(pc1)
        : "memory");
}

// ---------------------------------------------------------------------------
// A0: transpose x (B,C,W,H) = [bc][wh] row-major  ->  xT [wh][bc]
// ---------------------------------------------------------------------------
__global__ __launch_bounds__(256) void k_transpose_x(const float* __restrict__ x,
                                                     float* __restrict__ xT) {
    __shared__ float tile[64][65];
    int bc0 = blockIdx.x * 64;
    int wh0 = blockIdx.y * 64;
    int xcol = threadIdx.x & 63;
    int yrow = threadIdx.x >> 6;
    for (int yy = yrow; yy < 64; yy += 4)
        tile[yy][xcol] = x[(size_t)(bc0 + yy) * WH_ + wh0 + xcol];
    __syncthreads();
    for (int yy = yrow; yy < 64; yy += 4)
        xT[(size_t)(wh0 + yy) * (B_*C_) + bc0 + xcol] = tile[xcol][yy];
}

// ---------------------------------------------------------------------------
// A: GEMM  xp[m][g] = sum_c A[m][c]*Wx[c][g] + bias[g],  m = wh*8+b (16384)
// BM=64, BN=128, BK=32; 256 threads; micro-tile 8m x 4n
// ---------------------------------------------------------------------------
#define BM 64
#define BN 128
#define BK 32
#define AS_STRIDE 68
#define BS_STRIDE 132

__global__ __launch_bounds__(256) void k_xproj(const float* __restrict__ xT,
                                               const float* __restrict__ Wx,
                                               const float* __restrict__ bias,
                                               float* __restrict__ xp) {
    __shared__ float As[BK * AS_STRIDE];
    __shared__ float Bs[BK * BS_STRIDE];

    int bid = blockIdx.x;
    int xcd = bid & 7;
    int slot = bid >> 3;
    int mt = xcd * 32 + slot / 10;
    int nt = slot % 10;
    int m0 = mt * BM, n0 = nt * BN;
    int tid = threadIdx.x;

    int tm  = (tid >> 5) * 8;
    int tn4 = (tid & 31) * 4;

    float4 acc[8];
#pragma unroll
    for (int i = 0; i < 8; ++i) { acc[i].x = acc[i].y = acc[i].z = acc[i].w = 0.f; }

    int ar = tid >> 2, aq = tid & 3;
    int br = tid >> 3, bq = tid & 7;

    for (int kc = 0; kc < C_; kc += BK) {
        float4 av0 = *(const float4*)(xT + (size_t)(m0 + ar) * C_ + kc + aq * 4);
        float4 av1 = *(const float4*)(xT + (size_t)(m0 + ar) * C_ + kc + (aq + 4) * 4);
        float4 bv[4];
#pragma unroll
        for (int s = 0; s < 4; ++s)
            bv[s] = *(const float4*)(Wx + (size_t)(kc + br) * G_ + n0 + (bq + 8 * s) * 4);

        __syncthreads();
        As[(aq * 4 + 0) * AS_STRIDE + ar] = av0.x;
        As[(aq * 4 + 1) * AS_STRIDE + ar] = av0.y;
        As[(aq * 4 + 2) * AS_STRIDE + ar] = av0.z;
        As[(aq * 4 + 3) * AS_STRIDE + ar] = av0.w;
        As[((aq + 4) * 4 + 0) * AS_STRIDE + ar] = av1.x;
        As[((aq + 4) * 4 + 1) * AS_STRIDE + ar] = av1.y;
        As[((aq + 4) * 4 + 2) * AS_STRIDE + ar] = av1.z;
        As[((aq + 4) * 4 + 3) * AS_STRIDE + ar] = av1.w;
#pragma unroll
        for (int s = 0; s < 4; ++s)
            *(float4*)&Bs[br * BS_STRIDE + (bq + 8 * s) * 4] = bv[s];
        __syncthreads();

#pragma unroll
        for (int k = 0; k < BK; ++k) {
            float4 a0 = *(const float4*)&As[k * AS_STRIDE + tm];
            float4 a1 = *(const float4*)&As[k * AS_STRIDE + tm + 4];
            float4 b0 = *(const float4*)&Bs[k * BS_STRIDE + tn4];
            float am[8] = {a0.x, a0.y, a0.z, a0.w, a1.x, a1.y, a1.z, a1.w};
#pragma unroll
            for (int i = 0; i < 8; ++i) {
                acc[i].x += am[i] * b0.x;
                acc[i].y += am[i] * b0.y;
                acc[i].z += am[i] * b0.z;
                acc[i].w += am[i] * b0.w;
            }
        }
    }

    float4 bb = *(const float4*)(bias + n0 + tn4);
#pragma unroll
    for (int i = 0; i < 8; ++i) {
        float4 o;
        o.x = acc[i].x + bb.x; o.y = acc[i].y + bb.y;
        o.z = acc[i].z + bb.z; o.w = acc[i].w + bb.w;
        *(float4*)(xp + (size_t)(m0 + tm + i) * G_ + n0 + tn4) = o;
    }
}

// ---------------------------------------------------------------------------
// B: persistent wavefront scan. 256 blocks (1/CU, 96KB LDS), 512 threads.
// Block bid handles rows w = (bid>>3) and (bid>>3)+32, n-tile nt = bid&7.
// Thread = (kq = tid>>5: 16 K-slices of 32 over combined K=512, c0 = tid&31);
// owns 5 gate-cols x 8 batches. WEIGHTS REGISTER-RESIDENT: wr[5][32] loaded
// once -- zero VMEM in the per-step GEMM (r6 bottleneck).
// Cross-block h/c/flags via sc0sc1 bypass (r5 protocol, proven).
// ---------------------------------------------------------------------------
#define NT 32
#define NSL 16                      // K-slices
#define GP_B_STRIDE (NSL*160 + 8)   // 2568

__global__ __launch_bounds__(512, 2) void k_scan(const float* __restrict__ xp,
                                                 const float* __restrict__ Wh1,
                                                 const float* __restrict__ Wh2,
                                                 float* __restrict__ hbuf,
                                                 float* __restrict__ cbuf,
                                                 unsigned int* __restrict__ flags) {
    __shared__ float hs[2][B_ * HID_];        // 16 KB ([0] reused as fin)
    __shared__ float gp[B_ * GP_B_STRIDE];    // 80.25 KB

    int w0b = blockIdx.x >> 3;
    int nt  = blockIdx.x & 7;
    int n0  = nt * NT;
    int tid = threadIdx.x;

    int kq  = tid >> 5;             // 0..15
    int c0  = tid & 31;
    int sel = kq >> 3;              // 0: Wh1/h_left, 1: Wh2/h_up (wave-uniform)
    int kk0 = (kq & 7) * 32;
    const float* Wm = sel ? Wh2 : Wh1;
    const float* hbase = &hs[sel][0];

    // ---- one-time: weights into registers (160 VGPRs) ----
    float wr[5][32];
#pragma unroll
    for (int g = 0; g < 5; ++g)
#pragma unroll
        for (int k = 0; k < 32; ++k)
            wr[g][k] = Wm[(size_t)(kk0 + k) * G_ + g * 256 + n0 + c0];

    int b2 = tid >> 5, nn2 = tid & 31;   // update mapping (tid < 256)

    for (int rr = 0; rr < 2; ++rr) {
        int w = w0b + rr * 32;
        for (int h = 0; h < H_; ++h) {
            int wh = w * H_ + h;

            // ---- xp prefetch (independent of flags; hides L2/HBM latency) ----
            float xpre[3];
            int xb[3], xcc[3];
#pragma unroll
            for (int t = 0; t < 3; ++t) {
                int idx = tid + 512 * t;
                if (idx < 1280) {
                    xb[t] = idx / 160;
                    xcc[t] = idx - xb[t] * 160;
                    int jj = (xcc[t] >> 5) * 256 + n0 + (xcc[t] & 31);
                    xpre[t] = xp[((size_t)wh * B_ + xb[t]) * G_ + jj];
                }
            }

            // ---- poll producer flags (wave 0, 16 lanes) ----
            if (tid < 64) {
                const unsigned* fp = nullptr;
                if (tid < 8) { if (w > 0) fp = flags + (size_t)(wh - H_) * 8 + tid; }
                else if (tid < 16) { if (h > 0) fp = flags + (size_t)(wh - 1) * 8 + (tid - 8); }
                bool pending = (fp != nullptr);
                for (;;) {
                    if (pending && ldg_byp_u32v(fp) != 0) pending = false;
                    if (__ballot(pending) == 0) break;
                    __builtin_amdgcn_s_sleep(1);
                }
            }
            __syncthreads();

            // ---- stage h_left, h_up (+ c_l, c_u for tid<256): one vmcnt ----
            float cl, cu;
            {
                bool vl = (h > 0), vu = (w > 0);
                const float* pl = vl ? hbuf + (size_t)(wh - 1) * CELL_STRIDE + tid * 4 : hbuf;
                const float* pu = vu ? hbuf + (size_t)(wh - H_) * CELL_STRIDE + tid * 4 : hbuf;
                bool cok = (tid < 256);
                const float* pcl = (vl && cok) ? cbuf + (size_t)(wh - 1) * CELL_STRIDE + b2 * HID_ + n0 + nn2 : cbuf;
                const float* pcu = (vu && cok) ? cbuf + (size_t)(wh - H_) * CELL_STRIDE + b2 * HID_ + n0 + nn2 : cbuf;
                v4f l0, u0;
                stage4(pl, pu, pcl, pcu, l0, u0, cl, cu);
                if (!vl) { l0 = 0.f; cl = 0.f; }
                if (!vu) { u0 = 0.f; cu = 0.f; }
                ((v4f*)hs[0])[tid] = l0;
                ((v4f*)hs[1])[tid] = u0;
            }
            __syncthreads();

            // ---- GEMM: pure LDS + FMA (no VMEM) ----
            float acc[5][8];
#pragma unroll
            for (int g = 0; g < 5; ++g)
#pragma unroll
                for (int b = 0; b < 8; ++b) acc[g][b] = 0.f;

#pragma unroll
            for (int k4 = 0; k4 < 8; ++k4) {
#pragma unroll
                for (int b = 0; b < 8; ++b) {
                    float4 hv = *(const float4*)&hbase[b * HID_ + kk0 + k4 * 4]; // broadcast
#pragma unroll
                    for (int g = 0; g < 5; ++g) {
                        acc[g][b] += hv.x * wr[g][k4 * 4 + 0];
                        acc[g][b] += hv.y * wr[g][k4 * 4 + 1];
                        acc[g][b] += hv.z * wr[g][k4 * 4 + 2];
                        acc[g][b] += hv.w * wr[g][k4 * 4 + 3];
                    }
                }
            }

            // partials gp[b][kq][c]
#pragma unroll
            for (int g = 0; g < 5; ++g)
#pragma unroll
                for (int b = 0; b < 8; ++b)
                    gp[b * GP_B_STRIDE + kq * 160 + g * 32 + c0] = acc[g][b];
            __syncthreads();

            // ---- reduce 16 K-slices + xp -> fin (= hs[0]) ----
            float* fin = hs[0];
#pragma unroll
            for (int t = 0; t < 3; ++t) {
                int idx = tid + 512 * t;
                if (idx < 1280) {
                    float s = xpre[t];
#pragma unroll
                    for (int q = 0; q < NSL; ++q)
                        s += gp[xb[t] * GP_B_STRIDE + q * 160 + xcc[t]];
                    fin[xb[t] * 160 + xcc[t]] = s;
                }
            }
            __syncthreads();

            // ---- cell update (tid < 256; cl/cu prefetched) ----
            if (tid < 256) {
                float iv = sigmoidf_(fin[b2 * 160 + 0 * 32 + nn2]);
                float f1 = sigmoidf_(fin[b2 * 160 + 1 * 32 + nn2]);
                float f2 = sigmoidf_(fin[b2 * 160 + 2 * 32 + nn2]);
                float ov = sigmoidf_(fin[b2 * 160 + 3 * 32 + nn2]);
                float cd = tanhf_(fin[b2 * 160 + 4 * 32 + nn2]);
                float cv = iv * cd + f1 * cl + f2 * cu;
                float hh = ov * tanhf_(cv);
                int n = n0 + nn2;
                stg_byp1(cbuf + (size_t)wh * CELL_STRIDE + b2 * HID_ + n, cv);
                stg_byp1(hbuf + (size_t)wh * CELL_STRIDE + b2 * HID_ + n, hh);
            }
            drain_stores();
            __syncthreads();    // all threads' stores at coherence point

            if (tid == 0)
                stg_byp_u32(&flags[(size_t)wh * 8 + nt], 1u);
        }
    }
}

// ---------------------------------------------------------------------------
// C1: BN partial stats
// ---------------------------------------------------------------------------
__global__ __launch_bounds__(256) void k_stats(const float* __restrict__ hbuf,
                                               float* __restrict__ ssum,
                                               float* __restrict__ ssq) {
    int t = threadIdx.x;
    size_t r0 = (size_t)blockIdx.x * 64;
    float s = 0.f, q = 0.f;
    for (int r = 0; r < 64; ++r) {
        float v = hbuf[(r0 + r) * HID_ + t];
        s += v; q += v * v;
    }
    atomicAdd(&ssum[t], s);
    atomicAdd(&ssq[t], q);
}

__global__ void k_finstats(const float* __restrict__ ssum, const float* __restrict__ ssq,
                           float* __restrict__ mean, float* __restrict__ rinv) {
    int t = threadIdx.x;
    const float inv_n = 1.0f / 16384.0f;
    float m = ssum[t] * inv_n;
    float v = ssq[t] * inv_n - m * m;
    mean[t] = m;
    rinv[t] = rsqrtf(v + 1e-5f);
}

// ---------------------------------------------------------------------------
// C2: transpose (wh,b,n) -> (b,n,wh); fused BN+tanh for out
// ---------------------------------------------------------------------------
__global__ __launch_bounds__(256) void k_out(const float* __restrict__ hbuf,
                                             const float* __restrict__ cbuf,
                                             const float* __restrict__ mean,
                                             const float* __restrict__ rinv,
                                             const float* __restrict__ gamma,
                                             const float* __restrict__ beta,
                                             float* __restrict__ outp) {
    __shared__ float tile[64][65];
    int bi = blockIdx.x;
    int b = bi >> 7;
    int rem = bi & 127;
    int wh0 = (rem >> 2) * 64;
    int n0 = (rem & 3) * 64;
    int xcol = threadIdx.x & 63;
    int yrow = threadIdx.x >> 6;

    float* out0   = outp;
    float* state0 = outp + (size_t)B_ * HID_ * WH_;
    float* cell0  = state0 + (size_t)B_ * HID_ * WH_;

    for (int yy = yrow; yy < 64; yy += 4)
        tile[yy][xcol] = hbuf[((size_t)(wh0 + yy) * B_ + b) * HID_ + n0 + xcol];
    __syncthreads();
    for (int yy = yrow; yy < 64; yy += 4) {
        int n = n0 + yy;
        float sv = tile[xcol][yy];
        size_t oidx = ((size_t)b * HID_ + n) * WH_ + wh0 + xcol;
        state0[oidx] = sv;
        float xn = (sv - mean[n]) * rinv[n];
        out0[oidx] = tanhf_(xn * gamma[n] + beta[n]);
    }
    __syncthreads();

    for (int yy = yrow; yy < 64; yy += 4)
        tile[yy][xcol] = cbuf[((size_t)(wh0 + yy) * B_ + b) * HID_ + n0 + xcol];
    __syncthreads();
    for (int yy = yrow; yy < 64; yy += 4) {
        int n = n0 + yy;
        size_t oidx = ((size_t)b * HID_ + n) * WH_ + wh0 + xcol;
        cell0[oidx] = tile[xcol][yy];
    }
}

// ---------------------------------------------------------------------------
extern "C" void kernel_launch(void* const* d_in, const int* in_sizes, int n_in,
                              void* d_out, int out_size, void* d_ws, size_t ws_size,
                              hipStream_t stream) {
    const float* x     = (const float*)d_in[0];
    const float* Wx    = (const float*)d_in[1];
    const float* Wh1   = (const float*)d_in[2];
    const float* Wh2   = (const float*)d_in[3];
    const float* bias  = (const float*)d_in[4];
    const float* gamma = (const float*)d_in[5];
    const float* beta  = (const float*)d_in[6];
    float* out = (float*)d_out;
    float* ws  = (float*)d_ws;

    float* xp   = ws;                       // 20,971,520 floats
    float* xT   = ws + 20971520;            // 8,388,608 floats (dead after xproj)
    float* hbuf = xT;                       // alias
    float* cbuf = xT + 4194304;             // alias
    float* ssum = ws + 29360128;
    float* ssq  = ssum + 256;
    float* mean = ssum + 512;
    float* rinv = ssum + 768;
    unsigned int* flags = (unsigned int*)(ws + 29361152);  // 16384 u32

    k_transpose_x<<<dim3(64, 32), 256, 0, stream>>>(x, xT);
    k_xproj<<<2560, 256, 0, stream>>>(xT, Wx, bias, xp);

    hipMemsetAsync(ssum, 0, (1024 + 16384) * sizeof(unsigned int), stream);

    k_scan<<<256, 512, 0, stream>>>(xp, Wh1, Wh2, hbuf, cbuf, flags);

    k_stats<<<256, 256, 0, stream>>>(hbuf, ssum, ssq);
    k_finstats<<<1, 256, 0, stream>>>(ssum, ssq, mean, rinv);
    k_out<<<8 * 32 * 4, 256, 0, stream>>>(hbuf, cbuf, mean, rinv, gamma, beta, out);
}